// Round 2
// baseline (554.520 us; speedup 1.0000x reference)
//
#include <hip/hip_runtime.h>

#define B 4
#define L 96
#define V 207
#define H 8
#define E 64
#define C 512            // H*E
#define LS (V*C)         // stride between consecutive l rows = 105984
#define TOPK 4
#define LPAD 68          // padded LDS row stride (floats) for corr kernel
#define TPAD 132         // padded LDS row stride (floats) for agg transpose slab

// workspace layout (byte offsets)
#define MV_OFF 0                          // float mean_value[B*V*L]
#define IDX_OFF (B*V*L*4)                 // int   index[V*TOPK]
#define TC_OFF  (IDX_OFF + V*TOPK*4)      // float tmp_corr[B*V*TOPK]

// ---------------------------------------------------------------------------
// Kernel 1: per (b,v), mean over channels of circular cross-correlation.
// mean_value[b,v,tau] = (1/512) * sum_t sum_c Q[(t+tau)%L, c] * K[t, c]
// Computed as the 96x96x512 Gram matrix with fused circulant-diagonal sums.
// ---------------------------------------------------------------------------
__global__ __launch_bounds__(256) void corr_mean_kernel(
        const float* __restrict__ q, const float* __restrict__ k,
        float* __restrict__ mv) {
    __shared__ float Qs[L * LPAD];
    __shared__ float Ks[L * LPAD];
    __shared__ float corr[L];

    const int bid = blockIdx.x;
    const int b = bid / V;
    const int v = bid % V;
    const int tid = threadIdx.x;
    const int ti = tid >> 4;     // 0..15 -> t1 = ti + 16*i
    const int tj = tid & 15;     // 0..15 -> t2 = tj + 16*j

    const size_t base = ((size_t)b * L * V + v) * (size_t)C;

    float acc[6][6];
#pragma unroll
    for (int i = 0; i < 6; i++)
#pragma unroll
        for (int j = 0; j < 6; j++) acc[i][j] = 0.f;

    for (int c0 = 0; c0 < C; c0 += 64) {
        // Stage 96 rows x 64 channels of Q and K into LDS (float4 loads).
#pragma unroll
        for (int it = 0; it < 6; it++) {
            const int id = tid + it * 256;        // 0..1535
            const int t = id >> 4;                // row 0..95
            const int fc = (id & 15) << 2;        // channel 0..60 step 4
            const size_t g = base + (size_t)t * LS + c0 + fc;
            const float4 qv = *(const float4*)(q + g);
            const float4 kv = *(const float4*)(k + g);
            *(float4*)(Qs + t * LPAD + fc) = qv;
            *(float4*)(Ks + t * LPAD + fc) = kv;
        }
        __syncthreads();

#pragma unroll 4
        for (int cc = 0; cc < 64; cc++) {
            float qr[6], kr[6];
#pragma unroll
            for (int i = 0; i < 6; i++) qr[i] = Qs[(ti + 16 * i) * LPAD + cc];
#pragma unroll
            for (int j = 0; j < 6; j++) kr[j] = Ks[(tj + 16 * j) * LPAD + cc];
#pragma unroll
            for (int i = 0; i < 6; i++)
#pragma unroll
                for (int j = 0; j < 6; j++)
                    acc[i][j] = fmaf(qr[i], kr[j], acc[i][j]);
        }
        __syncthreads();
    }

    if (tid < L) corr[tid] = 0.f;
    __syncthreads();

    // Fused diagonal reduction: acc[i][j] is S[t1,t2] with
    // t1 = ti+16i, t2 = tj+16j; contributes to tau = (t1 - t2) mod 96.
#pragma unroll
    for (int d = -5; d <= 5; d++) {
        float s = 0.f;
#pragma unroll
        for (int i = 0; i < 6; i++) {
            const int j = i - d;
            if (j >= 0 && j < 6) s += acc[i][j];
        }
        int tau = ti - tj + 16 * d;
        tau = ((tau % L) + L) % L;
        atomicAdd(&corr[tau], s);
    }
    __syncthreads();

    if (tid < L) mv[((size_t)b * V + v) * L + tid] = corr[tid] * (1.0f / 512.0f);
}

// ---------------------------------------------------------------------------
// Kernel 2: per v — sum over b, serial top-4, per-b softmax of gathered weights
// ---------------------------------------------------------------------------
__global__ __launch_bounds__(128) void topk_softmax_kernel(
        const float* __restrict__ mv, int* __restrict__ idx,
        float* __restrict__ tc) {
    __shared__ float gm[L];
    __shared__ int sidx[TOPK];
    const int v = blockIdx.x;
    const int tid = threadIdx.x;

    if (tid < L) {
        float s = 0.f;
        for (int b = 0; b < B; b++) s += mv[((size_t)b * V + v) * L + tid];
        gm[tid] = s;
    }
    __syncthreads();

    if (tid == 0) {
        for (int kk = 0; kk < TOPK; kk++) {
            float best = -1e30f;
            int bi = 0;
            for (int t = 0; t < L; t++)
                if (gm[t] > best) { best = gm[t]; bi = t; }
            sidx[kk] = bi;
            gm[bi] = -1e30f;
        }
        for (int kk = 0; kk < TOPK; kk++) idx[v * TOPK + kk] = sidx[kk];
    }
    __syncthreads();

    if (tid < B) {
        const int b = tid;
        float w[TOPK];
        float m = -1e30f;
        for (int kk = 0; kk < TOPK; kk++) {
            w[kk] = mv[((size_t)b * V + v) * L + sidx[kk]];
            m = fmaxf(m, w[kk]);
        }
        float s = 0.f;
        for (int kk = 0; kk < TOPK; kk++) { w[kk] = expf(w[kk] - m); s += w[kk]; }
        const float inv = 1.f / s;
        for (int kk = 0; kk < TOPK; kk++)
            tc[((size_t)b * V + v) * TOPK + kk] = w[kk] * inv;
    }
}

// ---------------------------------------------------------------------------
// Kernel 3: out[b,l,v, e*8+h] = sum_kk w[b,v,kk] * values[b,(l+idx[v,kk])%L, v, h*64+e]
// NOTE the H<->E transpose: output channel order is (E,H), input is (H,E).
// One block per (b, v, e-quarter). The 96-row x 128-input-channel slab
// (h in [0,8), e in [e0,e0+16)) is staged into LDS ALREADY TRANSPOSED to
// output channel order T[l][ (e-e0)*8 + h ], so compute reads are contiguous
// ds_read_b128 and global writes are perfectly coalesced.
// ---------------------------------------------------------------------------
__global__ __launch_bounds__(256) void agg_kernel(
        const float* __restrict__ val, const float* __restrict__ tc,
        const int* __restrict__ idx, float* __restrict__ out) {
    __shared__ __attribute__((aligned(16))) float T[L * TPAD];  // ~50 KiB
    __shared__ int sidx[TOPK];
    __shared__ float sw[TOPK];

    const int bid = blockIdx.x;
    const int qtr = bid & 3;              // e-quarter: e in [qtr*16, qtr*16+16)
    const int bv = bid >> 2;
    const int b = bv / V;
    const int v = bv % V;
    const int tid = threadIdx.x;
    const int e0 = qtr * 16;

    const size_t base = ((size_t)b * L * V + v) * (size_t)C;

    if (tid < TOPK) {
        sidx[tid] = idx[v * TOPK + tid];
        sw[tid] = tc[((size_t)b * V + v) * TOPK + tid];
    }

    // Stage with transpose: id in [0,3072): l = id>>5, h = (id&31)>>2, f4 = id&3.
    // Read float4 of input channels h*64 + e0 + f4*4 + s (s=0..3);
    // write scalars to T[l][(f4*4+s)*8 + h].
#pragma unroll
    for (int it = 0; it < 12; it++) {
        const int id = tid + it * 256;
        const int l = id >> 5;
        const int h = (id & 31) >> 2;
        const int f4 = id & 3;
        const float4 r = *(const float4*)(val + base + (size_t)l * LS + h * 64 + e0 + f4 * 4);
        float* dst = T + l * TPAD + f4 * 32 + h;
        dst[0]  = r.x;
        dst[8]  = r.y;
        dst[16] = r.z;
        dst[24] = r.w;
    }
    __syncthreads();

    const float w0 = sw[0], w1 = sw[1], w2 = sw[2], w3 = sw[3];
    const int i0 = sidx[0], i1 = sidx[1], i2 = sidx[2], i3 = sidx[3];

    // Output: id in [0,3072): l = id>>5, m = id&31 -> output float4 at
    // channel qtr*128 + 4m (contiguous, coalesced).
#pragma unroll
    for (int it = 0; it < 12; it++) {
        const int id = tid + it * 256;
        const int l = id >> 5;
        const int m = id & 31;
        int l0 = l + i0; if (l0 >= L) l0 -= L;
        int l1 = l + i1; if (l1 >= L) l1 -= L;
        int l2 = l + i2; if (l2 >= L) l2 -= L;
        int l3 = l + i3; if (l3 >= L) l3 -= L;
        const float4 r0 = *(const float4*)(T + l0 * TPAD + m * 4);
        const float4 r1 = *(const float4*)(T + l1 * TPAD + m * 4);
        const float4 r2 = *(const float4*)(T + l2 * TPAD + m * 4);
        const float4 r3 = *(const float4*)(T + l3 * TPAD + m * 4);
        float4 o;
        o.x = w0 * r0.x + w1 * r1.x + w2 * r2.x + w3 * r3.x;
        o.y = w0 * r0.y + w1 * r1.y + w2 * r2.y + w3 * r3.y;
        o.z = w0 * r0.z + w1 * r1.z + w2 * r2.z + w3 * r3.z;
        o.w = w0 * r0.w + w1 * r1.w + w2 * r2.w + w3 * r3.w;
        *(float4*)(out + base + (size_t)l * LS + qtr * 128 + m * 4) = o;
    }
}

extern "C" void kernel_launch(void* const* d_in, const int* in_sizes, int n_in,
                              void* d_out, int out_size, void* d_ws, size_t ws_size,
                              hipStream_t stream) {
    const float* q = (const float*)d_in[0];
    const float* k = (const float*)d_in[1];
    const float* val = (const float*)d_in[2];
    float* out = (float*)d_out;
    char* ws = (char*)d_ws;
    float* mv = (float*)(ws + MV_OFF);
    int* idx = (int*)(ws + IDX_OFF);
    float* tc = (float*)(ws + TC_OFF);

    corr_mean_kernel<<<B * V, 256, 0, stream>>>(q, k, mv);
    topk_softmax_kernel<<<V, 128, 0, stream>>>(mv, idx, tc);
    agg_kernel<<<B * V * 4, 256, 0, stream>>>(val, tc, idx, out);
}